// Round 3
// baseline (377.147 us; speedup 1.0000x reference)
//
#include <hip/hip_runtime.h>
#include <hip/hip_bf16.h>
#include <cstdint>

// Problem: B=128, T=512, F=512, M=512 (fixed by setup_inputs).
// out[b,m,f] = gelu( sum_t xn[b,t,f]*W[m,t] + bias[m] ) + x[b,m,f]
// xn = layernorm over t per (b,f), * gamma[t] + beta[t].
//
// Round-3 structure: two homogeneous kernels.
//   ln_kernel:   x -> xn (bf16, MFMA-B-fragment-major chunks in ws). Pure streaming.
//   gemm_kernel: big GEMM M=512,K=512,N=65536 from fragment-major W and xn.
//                Zero LDS, zero barriers; waves independent; register prefetch.

#define B_ 128
#define T_ 512
#define F_ 512
#define M_ 512

typedef __attribute__((ext_vector_type(8))) short bf16x8;
typedef __attribute__((ext_vector_type(4))) float f32x4;

static __device__ __forceinline__ unsigned short f2bf(float f) {
    unsigned int u = __float_as_uint(f);
    unsigned int r = u + 0x7FFFu + ((u >> 16) & 1u);
    return (unsigned short)(r >> 16);
}

// ---------------- W fp32 -> bf16 fragment-major permute --------------------------
// Wq chunks [kc(16)][mg(32)][lane(64)], 16 B each:
//   chunk(kc,mg,lane) = W[m = mg*16 + (lane&15)][k = kc*32 + (lane>>4)*8 .. +8)
__global__ void wconv_kernel(const float* __restrict__ W, unsigned short* __restrict__ Wq) {
    int idx  = blockIdx.x * 256 + threadIdx.x;   // 32768 chunks
    int lane = idx & 63;
    int mg   = (idx >> 6) & 31;
    int kc   = idx >> 11;
    int m = mg * 16 + (lane & 15);
    int k = kc * 32 + (lane >> 4) * 8;
    const float* src = W + (size_t)m * 512 + k;
    float4 v0 = *(const float4*)(src);
    float4 v1 = *(const float4*)(src + 4);
    uint4 o;
    o.x = (unsigned int)f2bf(v0.x) | ((unsigned int)f2bf(v0.y) << 16);
    o.y = (unsigned int)f2bf(v0.z) | ((unsigned int)f2bf(v0.w) << 16);
    o.z = (unsigned int)f2bf(v1.x) | ((unsigned int)f2bf(v1.y) << 16);
    o.w = (unsigned int)f2bf(v1.z) | ((unsigned int)f2bf(v1.w) << 16);
    *(uint4*)(Wq + (size_t)idx * 8) = o;
}

// ---------------- LN kernel: x -> xq fragment-major bf16 -------------------------
// grid (16, 128), 512 threads. xq chunks [b(128)][kc(16)][fblk(32)][lane(64)], 16 B:
//   chunk(b,kc,fblk,lane) = xn[b][t = kc*32 + (lane>>4)*8 .. +8][f = fblk*16 + (lane&15)]
__global__ __launch_bounds__(512) void ln_kernel(
    const float* __restrict__ x, const float* __restrict__ gamma,
    const float* __restrict__ beta, unsigned short* __restrict__ xq)
{
    __shared__ float red_sum[512];
    __shared__ float red_sq[512];
    __shared__ float gS[512];
    __shared__ float bS[512];
    __shared__ float meanS[32];
    __shared__ float rstdS[32];

    const int tid   = threadIdx.x;
    const int w     = tid >> 6;
    const int lane  = tid & 63;
    const int batch = blockIdx.y;
    const int f0    = blockIdx.x * 32;

    gS[tid] = gamma[tid];
    bS[tid] = beta[tid];

    const int f  = lane & 31;
    const int tg = w * 2 + (lane >> 5);             // [0,16)
    float xv[32];
    {
        const float* xb = x + ((size_t)batch * T_ + (size_t)tg * 32) * F_ + f0 + f;
        float s = 0.f, q = 0.f;
        #pragma unroll
        for (int i = 0; i < 32; ++i) {
            float v = xb[(size_t)i * F_];
            xv[i] = v; s += v; q += v * v;
        }
        red_sum[tg * 32 + f] = s;
        red_sq [tg * 32 + f] = q;
    }
    __syncthreads();

    if (tid < 32) {
        float s = 0.f, q = 0.f;
        #pragma unroll
        for (int g = 0; g < 16; ++g) { s += red_sum[g * 32 + tid]; q += red_sq[g * 32 + tid]; }
        float mean = s * (1.0f / 512.0f);
        float var  = q * (1.0f / 512.0f) - mean * mean;
        meanS[tid] = mean;
        rstdS[tid] = rsqrtf(var + 1e-5f);
    }
    __syncthreads();

    {
        const float mean = meanS[f];
        const float rstd = rstdS[f];
        const size_t cbase = ((size_t)(batch * 16 + tg) * 32 + (f0 >> 4) + (f >> 4)) * 64 + (f & 15);
        #pragma unroll
        for (int c = 0; c < 4; ++c) {               // c == q4 chunk: t = tg*32 + c*8 ..
            const int t0 = tg * 32 + c * 8;
            unsigned int pr[4];
            #pragma unroll
            for (int h = 0; h < 4; ++h) {
                float a0 = rstd * gS[t0 + 2 * h];
                float v0 = xv[c * 8 + 2 * h] * a0 + (bS[t0 + 2 * h] - mean * a0);
                float a1 = rstd * gS[t0 + 2 * h + 1];
                float v1 = xv[c * 8 + 2 * h + 1] * a1 + (bS[t0 + 2 * h + 1] - mean * a1);
                pr[h] = (unsigned int)f2bf(v0) | ((unsigned int)f2bf(v1) << 16);
            }
            uint4 pk; pk.x = pr[0]; pk.y = pr[1]; pk.z = pr[2]; pk.w = pr[3];
            *(uint4*)(xq + (cbase + (size_t)c * 16) * 8) = pk;   // coalesced 256B segments
        }
    }
}

// ---------------- GEMM kernel: zero-LDS, barrier-free ----------------------------
// grid (8, 128): blockIdx.x = mb(2) x ft(4); 256 threads = 4 waves.
// Wave tile: 64 m x 128 f. Block: 256 m x 128 f (waves share B-frag addrs -> L1 hits).
__global__ __launch_bounds__(256, 2) void gemm_kernel(
    const float* __restrict__ x, const unsigned short* __restrict__ Wq,
    const unsigned short* __restrict__ xq, const float* __restrict__ bias,
    float* __restrict__ out)
{
    const int tid  = threadIdx.x;
    const int w    = tid >> 6;
    const int lane = tid & 63;
    const int mb   = blockIdx.x & 1;
    const int ft   = blockIdx.x >> 1;
    const int b    = blockIdx.y;
    const int lr   = lane & 15;
    const int q4   = lane >> 4;

    const unsigned short* wbase = Wq + ((size_t)(mb * 16 + w * 4) * 64 + lane) * 8;
    // + (kc*32 + mi)*512 shorts per chunk step
    const unsigned short* xbase = xq + (((size_t)(b * 16) * 32) + ft * 8) * 512 + (size_t)lane * 8;
    // + (kc*32 + fi)*512 shorts per chunk step

    f32x4 acc[4][8];
    #pragma unroll
    for (int mi = 0; mi < 4; ++mi)
        #pragma unroll
        for (int fi = 0; fi < 8; ++fi)
            acc[mi][fi] = (f32x4){0.f, 0.f, 0.f, 0.f};

    bf16x8 A0[4], A1[4], B0[8], B1[8];
    #pragma unroll
    for (int mi = 0; mi < 4; ++mi) A0[mi] = *(const bf16x8*)(wbase + (size_t)mi * 512);
    #pragma unroll
    for (int fi = 0; fi < 8; ++fi) B0[fi] = *(const bf16x8*)(xbase + (size_t)fi * 512);

    for (int kc = 0; kc < 16; kc += 2) {
        // prefetch kc+1 while computing kc
        #pragma unroll
        for (int mi = 0; mi < 4; ++mi)
            A1[mi] = *(const bf16x8*)(wbase + (size_t)((kc + 1) * 32 + mi) * 512);
        #pragma unroll
        for (int fi = 0; fi < 8; ++fi)
            B1[fi] = *(const bf16x8*)(xbase + (size_t)((kc + 1) * 32 + fi) * 512);
        #pragma unroll
        for (int mi = 0; mi < 4; ++mi)
            #pragma unroll
            for (int fi = 0; fi < 8; ++fi)
                acc[mi][fi] = __builtin_amdgcn_mfma_f32_16x16x32_bf16(A0[mi], B0[fi], acc[mi][fi], 0, 0, 0);
        // prefetch kc+2 while computing kc+1
        if (kc + 2 < 16) {
            #pragma unroll
            for (int mi = 0; mi < 4; ++mi)
                A0[mi] = *(const bf16x8*)(wbase + (size_t)((kc + 2) * 32 + mi) * 512);
            #pragma unroll
            for (int fi = 0; fi < 8; ++fi)
                B0[fi] = *(const bf16x8*)(xbase + (size_t)((kc + 2) * 32 + fi) * 512);
        }
        #pragma unroll
        for (int mi = 0; mi < 4; ++mi)
            #pragma unroll
            for (int fi = 0; fi < 8; ++fi)
                acc[mi][fi] = __builtin_amdgcn_mfma_f32_16x16x32_bf16(A1[mi], B1[fi], acc[mi][fi], 0, 0, 0);
    }

    // epilogue: bias + exact gelu + residual
    #pragma unroll
    for (int mi = 0; mi < 4; ++mi) {
        const int mbase = mb * 256 + w * 64 + mi * 16 + q4 * 4;
        #pragma unroll
        for (int r = 0; r < 4; ++r) {
            const int m = mbase + r;
            const float bv = bias[m];
            const size_t orow = ((size_t)(b * 512 + m)) * 512 + (size_t)(ft * 128 + lr);
            #pragma unroll
            for (int fi = 0; fi < 8; ++fi) {
                float y = acc[mi][fi][r] + bv;
                float gl = 0.5f * y * (1.0f + erff(y * 0.70710678118654752f));
                size_t o = orow + (size_t)(fi * 16);
                out[o] = gl + x[o];
            }
        }
    }
}

// ---------------- fallback fused kernel (proven, 162 us) -------------------------
#define XN_STRIDE 520
__global__ __launch_bounds__(512, 4) void timemix_fused(
    const float* __restrict__ x, const float* __restrict__ gamma,
    const float* __restrict__ beta, const unsigned short* __restrict__ Wq,
    const float* __restrict__ bias, float* __restrict__ out)
{
    __shared__ __align__(16) unsigned char smem[37632];
    unsigned char* xnS = smem;
    float* gS    = (float*)(smem + 33280);
    float* bS    = (float*)(smem + 35328);
    float* meanS = (float*)(smem + 37376);
    float* rstdS = (float*)(smem + 37504);
    __shared__ float red_sum[512];
    __shared__ float red_sq[512];

    const int tid = threadIdx.x, w = tid >> 6, lane = tid & 63;
    const int batch = blockIdx.y, f0 = blockIdx.x * 32;
    gS[tid] = gamma[tid]; bS[tid] = beta[tid];
    const int f = lane & 31, tg = w * 2 + (lane >> 5);
    float xv[32];
    {
        const float* xb = x + ((size_t)batch * T_ + (size_t)tg * 32) * F_ + f0 + f;
        float s = 0.f, q = 0.f;
        #pragma unroll
        for (int i = 0; i < 32; ++i) { float v = xb[(size_t)i * F_]; xv[i] = v; s += v; q += v * v; }
        red_sum[tg * 32 + f] = s; red_sq[tg * 32 + f] = q;
    }
    __syncthreads();
    if (tid < 32) {
        float s = 0.f, q = 0.f;
        #pragma unroll
        for (int g = 0; g < 16; ++g) { s += red_sum[g * 32 + tid]; q += red_sq[g * 32 + tid]; }
        float mean = s * (1.0f / 512.0f), var = q * (1.0f / 512.0f) - mean * mean;
        meanS[tid] = mean; rstdS[tid] = rsqrtf(var + 1e-5f);
    }
    __syncthreads();
    {
        const float mean = meanS[f], rstd = rstdS[f];
        #pragma unroll
        for (int c = 0; c < 4; ++c) {
            const int t0 = tg * 32 + c * 8;
            unsigned int pr[4];
            #pragma unroll
            for (int h = 0; h < 4; ++h) {
                float a0 = rstd * gS[t0 + 2 * h];
                float v0 = xv[c * 8 + 2 * h] * a0 + (bS[t0 + 2 * h] - mean * a0);
                float a1 = rstd * gS[t0 + 2 * h + 1];
                float v1 = xv[c * 8 + 2 * h + 1] * a1 + (bS[t0 + 2 * h + 1] - mean * a1);
                pr[h] = (unsigned int)f2bf(v0) | ((unsigned int)f2bf(v1) << 16);
            }
            uint4 pk; pk.x = pr[0]; pk.y = pr[1]; pk.z = pr[2]; pk.w = pr[3];
            *(uint4*)(xnS + (size_t)f * (XN_STRIDE * 2) + t0 * 2) = pk;
        }
    }
    __syncthreads();
    const int lr = lane & 15, q4 = lane >> 4;
    const unsigned short* wbase = Wq + ((size_t)(w * 4) * 64 + lane) * 8;
    f32x4 acc[4][2];
    #pragma unroll
    for (int mi = 0; mi < 4; ++mi)
        #pragma unroll
        for (int fi = 0; fi < 2; ++fi) acc[mi][fi] = (f32x4){0.f, 0.f, 0.f, 0.f};
    bf16x8 aA[4], aB[4];
    #pragma unroll
    for (int mi = 0; mi < 4; ++mi) aA[mi] = *(const bf16x8*)(wbase + (size_t)mi * 512);
    for (int kc = 0; kc < 16; kc += 2) {
        #pragma unroll
        for (int mi = 0; mi < 4; ++mi)
            aB[mi] = *(const bf16x8*)(wbase + (size_t)(kc + 1) * 16384 + (size_t)mi * 512);
        {
            bf16x8 b0 = *(const bf16x8*)(xnS + (size_t)lr * (XN_STRIDE * 2) + kc * 64 + q4 * 16);
            bf16x8 b1 = *(const bf16x8*)(xnS + (size_t)(16 + lr) * (XN_STRIDE * 2) + kc * 64 + q4 * 16);
            #pragma unroll
            for (int mi = 0; mi < 4; ++mi) {
                acc[mi][0] = __builtin_amdgcn_mfma_f32_16x16x32_bf16(aA[mi], b0, acc[mi][0], 0, 0, 0);
                acc[mi][1] = __builtin_amdgcn_mfma_f32_16x16x32_bf16(aA[mi], b1, acc[mi][1], 0, 0, 0);
            }
        }
        if (kc + 2 < 16) {
            #pragma unroll
            for (int mi = 0; mi < 4; ++mi)
                aA[mi] = *(const bf16x8*)(wbase + (size_t)(kc + 2) * 16384 + (size_t)mi * 512);
        }
        {
            bf16x8 b0 = *(const bf16x8*)(xnS + (size_t)lr * (XN_STRIDE * 2) + (kc + 1) * 64 + q4 * 16);
            bf16x8 b1 = *(const bf16x8*)(xnS + (size_t)(16 + lr) * (XN_STRIDE * 2) + (kc + 1) * 64 + q4 * 16);
            #pragma unroll
            for (int mi = 0; mi < 4; ++mi) {
                acc[mi][0] = __builtin_amdgcn_mfma_f32_16x16x32_bf16(aB[mi], b0, acc[mi][0], 0, 0, 0);
                acc[mi][1] = __builtin_amdgcn_mfma_f32_16x16x32_bf16(aB[mi], b1, acc[mi][1], 0, 0, 0);
            }
        }
    }
    #pragma unroll
    for (int mi = 0; mi < 4; ++mi) {
        const int mbase = w * 64 + mi * 16 + q4 * 4;
        #pragma unroll
        for (int r = 0; r < 4; ++r) {
            const int m = mbase + r;
            const float bv = bias[m];
            #pragma unroll
            for (int fi = 0; fi < 2; ++fi) {
                float y = acc[mi][fi][r] + bv;
                float gl = 0.5f * y * (1.0f + erff(y * 0.70710678118654752f));
                size_t o = ((size_t)(batch * 512 + m)) * 512 + (size_t)(f0 + fi * 16 + lr);
                out[o] = gl + x[o];
            }
        }
    }
}

extern "C" void kernel_launch(void* const* d_in, const int* in_sizes, int n_in,
                              void* d_out, int out_size, void* d_ws, size_t ws_size,
                              hipStream_t stream) {
    const float* x     = (const float*)d_in[0];
    const float* gamma = (const float*)d_in[1];
    const float* beta  = (const float*)d_in[2];
    const float* W     = (const float*)d_in[3];
    const float* bias  = (const float*)d_in[4];
    float* out = (float*)d_out;

    unsigned short* Wq = (unsigned short*)d_ws;                       // 512 KB
    unsigned short* xq = (unsigned short*)((char*)d_ws + 524288);     // 67.1 MB

    wconv_kernel<<<dim3(128), 256, 0, stream>>>(W, Wq);
    if (ws_size >= (size_t)524288 + (size_t)B_ * 16 * 32 * 64 * 16) {
        ln_kernel<<<dim3(16, B_), 512, 0, stream>>>(x, gamma, beta, xq);
        gemm_kernel<<<dim3(8, B_), 256, 0, stream>>>(x, Wq, xq, bias, out);
    } else {
        timemix_fused<<<dim3(16, B_), 512, 0, stream>>>(x, gamma, beta, Wq, bias, out);
    }
}